// Round 6
// baseline (4708.275 us; speedup 1.0000x reference)
//
#include <hip/hip_runtime.h>

#define B_    8
#define N_    8192
#define M_    2000
#define K_    16
#define C1_   128
#define C2_   256
#define OUT_  100
#define SUBP_ 2048   // padded per-batch pitch for subsampled points (KNN2 candidates)

// ---------------------------------------------------------------- helpers
__device__ inline unsigned long long shflxor_u64(unsigned long long v, int m) {
    int lo = __shfl_xor((int)(v & 0xFFFFFFFFull), m, 64);
    int hi = __shfl_xor((int)(v >> 32), m, 64);
    return ((unsigned long long)(unsigned)hi << 32) | (unsigned)lo;
}

__device__ inline int cellOf(float x, float y, float z) {   // 4 x 4 x 8 = 128 cells
    int ix = (int)(x * 4.0f); ix = ix < 0 ? 0 : (ix > 3 ? 3 : ix);
    int iy = (int)(y * 4.0f); iy = iy < 0 ? 0 : (iy > 3 ? 3 : iy);
    int iz = (int)(z * 8.0f); iz = iz < 0 ? 0 : (iz > 7 ? 7 : iz);
    return (ix << 5) | (iy << 3) | iz;
}

// ---------------------------------------------------------------- prep: coords -> float4(x,y,z,|p|^2); pad sub4 sentinels
__global__ __launch_bounds__(256) void prep_kernel(const float* __restrict__ x,
                                                   float4* __restrict__ coords4,
                                                   float4* __restrict__ sub4) {
    int i = blockIdx.x * 256 + threadIdx.x;
    if (i < B_ * N_) {
        float xx = x[i*3+0], yy = x[i*3+1], zz = x[i*3+2];
        float ss = fmaf(zz, zz, fmaf(yy, yy, xx*xx));   // ((x^2+y^2)+z^2)
        coords4[i] = make_float4(xx, yy, zz, ss);
    }
    if (i < B_ * (SUBP_ - M_)) {   // sentinel pads: huge distance, never selected
        int b = i / (SUBP_ - M_), j = i % (SUBP_ - M_);
        sub4[b*SUBP_ + M_ + j] = make_float4(1e15f, 1e15f, 1e15f, 3e30f);
    }
}

// ---------------------------------------------------------------- FPS: spatially-pruned, LDS-resident
// R1-R4 post-mortem: register residency for 48 floats/thread is unobtainable
// (allocator spills/re-loads regardless of pins/launch_bounds; measured
// ~2400 cyc/iter = L2 re-read of 128 KB/block/iter). This version keeps all
// point data in LDS and prunes work spatially:
//  - counting-sort 8192 pts into 128 spatial cells (4x4x8) -> LDS SoA
//  - 128 groups of 64 sorted pts, per-group bbox (center, radius) + cached
//    packed key u64 = (f32bits(group max md)<<32) | ~orig_idx  (max-by-value,
//    tie -> smallest ORIGINAL index == jnp.argmax first-max semantics)
//  - per iteration: conservative per-group bound check (dc - r < sqrt(gmax),
//    margins 1.001x+1e-6 -> false-dirty harmless, false-clean impossible);
//    dirty groups compacted to a list, re-scanned by waves; winner = u64 max
//    over all 128 cached keys (clean groups' cached keys stay exactly valid).
// Synchronization: 2 barriers/iter.
//   window X (check)  = [barrier2(i-1), barrier1(i)]: writes dlist/dcnt[par],
//       reads gkey/gc*/gr; t==511 resets dcnt[par^1] (readers of that parity
//       finished before barrier2(i-1), next readers after barrier1(i+1)).
//   window Y (dirty)  = [barrier1(i), barrier2(i)]: reads dlist/dcnt[par],
//       sx/sy/sz/smd writes smd/gkey/gpos (each group owned by one wave).
//   window Z (winner) = [barrier2(i), barrier1(i+1)]: reads gkey/gpos/sx/y/z
//       (no writes to those in X). Fast waves entering X(i+1) write only
//       dlist/dcnt -> disjoint. Slow waves in Z block barrier1(i+1).
#define FPS_T 512

__global__ __launch_bounds__(FPS_T, 1) void fps_kernel(const float4* __restrict__ coords4,
                                                       int* __restrict__ fps_idx,
                                                       float4* __restrict__ sub4) {
    __shared__ float sx[N_], sy[N_], sz[N_], smd[N_];        // 128 KB
    __shared__ unsigned short sorig[N_];                      // 16 KB
    __shared__ float gcx[128], gcy[128], gcz[128], gr[128];   // 2 KB
    __shared__ unsigned long long gkey[128];                  // 1 KB
    __shared__ int gpos[128];                                 // winner sorted-pos per group
    __shared__ int dlist[2][128];
    __shared__ int dcnt[2];
    __shared__ int bins[128], bofs[128];

    int b = blockIdx.x, t = threadIdx.x;
    int lane = t & 63, wv = t >> 6;
    const float4* C = coords4 + b * N_;

    // ---------------- setup: counting sort by cell into LDS SoA
    if (t < 128) bins[t] = 0;
    __syncthreads();
    for (int j = 0; j < N_ / FPS_T; ++j) {        // pass 1: histogram
        float4 p = C[t + j * FPS_T];
        atomicAdd(&bins[cellOf(p.x, p.y, p.z)], 1);
    }
    __syncthreads();
    if (wv == 0) {                                 // exclusive scan of 128 bins, wave 0
        int a0 = bins[lane], a1 = bins[64 + lane];
        int i0 = a0, i1 = a1;
        for (int s = 1; s < 64; s <<= 1) { int n = __shfl_up(i0, s, 64); if (lane >= s) i0 += n; }
        int tot0 = __shfl(i0, 63, 64);
        for (int s = 1; s < 64; s <<= 1) { int n = __shfl_up(i1, s, 64); if (lane >= s) i1 += n; }
        bofs[lane]      = i0 - a0;
        bofs[64 + lane] = i1 - a1 + tot0;
    }
    __syncthreads();
    for (int j = 0; j < N_ / FPS_T; ++j) {        // pass 2: scatter
        int i = t + j * FPS_T;
        float4 p = C[i];
        int pos = atomicAdd(&bofs[cellOf(p.x, p.y, p.z)], 1);
        sx[pos] = p.x; sy[pos] = p.y; sz[pos] = p.z;
        smd[pos] = 1e30f;
        sorig[pos] = (unsigned short)i;
    }
    if (t == 0) { dcnt[0] = 0; dcnt[1] = 0; }
    __syncthreads();
    // group bboxes (groups = sorted runs of 64)
    for (int g = wv; g < 128; g += 8) {
        int p = g * 64 + lane;
        float x = sx[p], y = sy[p], z = sz[p];
        float mnx = x, mxx = x, mny = y, mxy = y, mnz = z, mxz = z;
        for (int s = 1; s < 64; s <<= 1) {
            mnx = fminf(mnx, __shfl_xor(mnx, s, 64)); mxx = fmaxf(mxx, __shfl_xor(mxx, s, 64));
            mny = fminf(mny, __shfl_xor(mny, s, 64)); mxy = fmaxf(mxy, __shfl_xor(mxy, s, 64));
            mnz = fminf(mnz, __shfl_xor(mnz, s, 64)); mxz = fmaxf(mxz, __shfl_xor(mxz, s, 64));
        }
        if (lane == 0) {
            gcx[g] = (mnx + mxx) * 0.5f; gcy[g] = (mny + mxy) * 0.5f; gcz[g] = (mnz + mxz) * 0.5f;
            float hx = (mxx - mnx) * 0.5f, hy = (mxy - mny) * 0.5f, hz = (mxz - mnz) * 0.5f;
            gr[g] = sqrtf(fmaf(hz, hz, fmaf(hy, hy, hx*hx))) * 1.001f + 1e-6f;  // inflated
            gkey[g] = ((unsigned long long)__float_as_uint(1e30f) << 32);       // forces all-dirty at i=1
            gpos[g] = g * 64;
        }
    }
    float4 P0 = C[0];                              // first pick = original index 0
    float Px = P0.x, Py = P0.y, Pz = P0.z;
    if (t == 0) { fps_idx[b*M_] = 0; sub4[b*SUBP_] = P0; }
    __syncthreads();

    // ---------------- main loop
    for (int i = 1; i < M_; ++i) {
        int par = i & 1;
        // window X: group checks -> dirty list
        if (t < 128) {
            float dx = Px - gcx[t], dy = Py - gcy[t], dz = Pz - gcz[t];
            float dc = sqrtf(fmaf(dz, dz, fmaf(dy, dy, dx*dx)));
            float gmax = __uint_as_float((unsigned)(gkey[t] >> 32));
            float sg = sqrtf(gmax) * 1.001f + 1e-6f;
            if (dc - gr[t] < sg) {                 // conservative: may not miss a true update
                int sl = atomicAdd(&dcnt[par], 1);
                dlist[par][sl] = t;
            }
        }
        if (t == 511) dcnt[par ^ 1] = 0;
        __syncthreads();
        // window Y: re-scan dirty groups (one wave per list entry, strided)
        int D = dcnt[par];
        for (int ii = wv; ii < D; ii += 8) {
            int g = dlist[par][ii];
            int p = g * 64 + lane;
            float x = sx[p], y = sy[p], z = sz[p];
            float dx = x - Px, dy = y - Py, dz = z - Pz;
            float d = fmaf(dz, dz, fmaf(dy, dy, dx*dx));    // same form as reference FPS
            float m = fminf(smd[p], d);
            smd[p] = m;
            unsigned long long mine = ((unsigned long long)__float_as_uint(m) << 32)
                                    | (unsigned)(~(unsigned)sorig[p]);   // unique low bits
            unsigned long long kr = mine;
            for (int s = 1; s < 64; s <<= 1) {
                unsigned long long o = shflxor_u64(kr, s);
                if (o > kr) kr = o;
            }
            unsigned long long bal = __ballot(mine == kr);  // exactly one lane (keys unique)
            int src = __ffsll(bal) - 1;
            if (lane == 0) { gkey[g] = kr; gpos[g] = g * 64 + src; }
        }
        __syncthreads();
        // window Z: global winner over 128 cached keys (every wave, redundant)
        unsigned long long k1 = gkey[lane], k2 = gkey[64 + lane];
        int myg = (k1 >= k2) ? lane : 64 + lane;
        unsigned long long mine2 = (k1 >= k2) ? k1 : k2;
        unsigned long long kk = mine2;
        for (int s = 1; s < 64; s <<= 1) {
            unsigned long long o = shflxor_u64(kk, s);
            if (o > kk) kk = o;
        }
        unsigned long long bal2 = __ballot(mine2 == kk);    // unique winner lane
        int src2 = __ffsll(bal2) - 1;
        int gwin = __shfl(myg, src2, 64);
        int pos = gpos[gwin];
        Px = sx[pos]; Py = sy[pos]; Pz = sz[pos];
        if (t == 0) {
            unsigned orig = (~(unsigned)(kk & 0xFFFFFFFFull)) & 0xFFFFu;
            float ssq = fmaf(Pz, Pz, fmaf(Py, Py, Px*Px));  // identical bits to prep
            fps_idx[b*M_ + i] = (int)orig;
            sub4[b*SUBP_ + i] = make_float4(Px, Py, Pz, ssq);
        }
    }
}

// ---------------------------------------------------------------- KNN: 1 wave per query, exact top-16 (set semantics)
template<int NCH, int PITCH>
__global__ __launch_bounds__(256) void knn_kernel(const float4* __restrict__ cand,
                                                  const float4* __restrict__ qarr,
                                                  int* __restrict__ outIdx) {
    int lane = threadIdx.x & 63;
    int q = blockIdx.x * 4 + (threadIdx.x >> 6);
    int b = q / M_, m = q % M_;
    const float4* Cb = cand + b * PITCH;
    float4 Q = qarr[b * SUBP_ + m];

    float v[16];
#pragma unroll
    for (int tt = 0; tt < 16; ++tt) v[tt] = 3.4e38f;

#pragma unroll 2
    for (int j = 0; j < NCH; ++j) {
        float4 c = Cb[j*64 + lane];
        float dot = fmaf(c.z, Q.z, fmaf(c.y, Q.y, c.x * Q.x));
        float d = fmaf(-2.0f, dot, Q.w + c.w);   // == (qq+ss) - 2*dot, single rounding
        v[15] = fminf(v[15], d);
#pragma unroll
        for (int tt = 15; tt >= 1; --tt) {       // restore sortedness: bubble toward 0
            float lo = fminf(v[tt-1], v[tt]);
            float hi = fmaxf(v[tt-1], v[tt]);
            v[tt-1] = lo; v[tt] = hi;
        }
    }

    float T = 0.0f;
    for (int r = 0; r < 16; ++r) {               // extract global min 16 times
        float g = v[0];
#pragma unroll
        for (int s = 1; s < 64; s <<= 1) g = fminf(g, __shfl_xor(g, s, 64));
        unsigned long long mk = __ballot(v[0] == g);
        int fl = __ffsll(mk) - 1;                // exactly one lane consumes
        if (lane == fl) {
#pragma unroll
            for (int tt = 0; tt < 15; ++tt) v[tt] = v[tt+1];
            v[15] = 3.4e38f;
        }
        T = g;
    }

    unsigned long long mlt = (1ull << lane) - 1ull;
    int base = q * K_;
    int cnt = 0;
    for (int j = 0; j < NCH; ++j) {              // all strictly-closer candidates (<= 15)
        float4 c = Cb[j*64 + lane];
        float dot = fmaf(c.z, Q.z, fmaf(c.y, Q.y, c.x * Q.x));
        float d = fmaf(-2.0f, dot, Q.w + c.w);
        bool lt = d < T;
        unsigned long long m1 = __ballot(lt);
        if (lt) outIdx[base + cnt + __popcll(m1 & mlt)] = j*64 + lane;
        cnt += __popcll(m1);
    }
    int rem = K_ - cnt;                          // >= 1; fill with earliest-index ties
    for (int j = 0; j < NCH && rem > 0; ++j) {
        float4 c = Cb[j*64 + lane];
        float dot = fmaf(c.z, Q.z, fmaf(c.y, Q.y, c.x * Q.x));
        float d = fmaf(-2.0f, dot, Q.w + c.w);
        bool eq = (d == T);
        unsigned long long m2 = __ballot(eq);
        int bef = __popcll(m2 & mlt);
        if (eq && bef < rem) outIdx[base + cnt + bef] = j*64 + lane;
        int take = __popcll(m2); if (take > rem) take = rem;
        cnt += take; rem -= take;
    }
}

// ---------------------------------------------------------------- layer 1: feats=[rel(3), ngh(3)] x W1[6,128], relu, max over k
__global__ __launch_bounds__(128) void layer1_kernel(const float4* __restrict__ coords4,
        const float4* __restrict__ sub4, const int* __restrict__ idx1,
        const float* __restrict__ W1, const float* __restrict__ b1,
        float* __restrict__ f1) {
    int q = blockIdx.x;
    int b = q / M_, m = q % M_;
    int c = threadIdx.x;
    __shared__ float4 ngh[K_];
    if (c < K_) ngh[c] = coords4[b*N_ + idx1[q*K_ + c]];
    __syncthreads();
    float4 Q = sub4[b*SUBP_ + m];
    float w0 = W1[c],        w1 = W1[C1_ + c],   w2 = W1[2*C1_ + c];
    float w3 = W1[3*C1_ + c], w4 = W1[4*C1_ + c], w5 = W1[5*C1_ + c];
    float bias = b1[c];
    float mx = -3.4e38f;
#pragma unroll
    for (int k = 0; k < K_; ++k) {
        float4 n = ngh[k];
        float rx = n.x - Q.x, ry = n.y - Q.y, rz = n.z - Q.z;
        float s = rx*w0; s = fmaf(ry,w1,s); s = fmaf(rz,w2,s);
        s = fmaf(n.x,w3,s); s = fmaf(n.y,w4,s); s = fmaf(n.z,w5,s);
        s += bias;
        s = fmaxf(s, 0.0f);
        mx = fmaxf(mx, s);
    }
    f1[q*C1_ + c] = mx;
}

// ---------------------------------------------------------------- layer 2: feats=[rel(3), fg(128)] x W2[131,256], relu, max over k
#define FPAD 20   // row pitch (floats): 16B-aligned rows
__global__ __launch_bounds__(64) void layer2_kernel(const float4* __restrict__ sub4,
        const float* __restrict__ f1, const int* __restrict__ idx2,
        const float* __restrict__ W2, const float* __restrict__ b2,
        float* __restrict__ f2) {
    int q = blockIdx.x;
    int b = q / M_, m = q % M_;
    int t = threadIdx.x;
    __shared__ __align__(16) float feat[(3 + C1_) * FPAD];  // feat[f][k], k=0..15
    __shared__ int nidx[K_];
    float4 Q = sub4[b*SUBP_ + m];
    if (t < K_) {
        int ik = idx2[q*K_ + t];
        nidx[t] = ik;
        float4 n = sub4[b*SUBP_ + ik];
        feat[0*FPAD + t] = n.x - Q.x;
        feat[1*FPAD + t] = n.y - Q.y;
        feat[2*FPAD + t] = n.z - Q.z;
    }
    __syncthreads();
    for (int e = t; e < K_ * C1_; e += 64) {    // stage gathered f1 rows: feat[3+cc][k]
        int k = e >> 7, cc = e & 127;
        feat[(3 + cc)*FPAD + k] = f1[(b*M_ + nidx[k])*C1_ + cc];
    }
    __syncthreads();

    float acc[K_][4];
#pragma unroll
    for (int k = 0; k < K_; ++k) { acc[k][0]=0.f; acc[k][1]=0.f; acc[k][2]=0.f; acc[k][3]=0.f; }
    int c0 = t * 4;                              // 4 channels per thread, 64 threads = 256 ch
    for (int f = 0; f < 3 + C1_; ++f) {
        float4 w  = *(const float4*)(W2 + f*C2_ + c0);
        const float* row = feat + f*FPAD;
        float4 g0 = *(const float4*)(row + 0);
        float4 g1 = *(const float4*)(row + 4);
        float4 g2 = *(const float4*)(row + 8);
        float4 g3 = *(const float4*)(row + 12);
        float gk[16] = {g0.x,g0.y,g0.z,g0.w, g1.x,g1.y,g1.z,g1.w,
                        g2.x,g2.y,g2.z,g2.w, g3.x,g3.y,g3.z,g3.w};
#pragma unroll
        for (int k = 0; k < K_; ++k) {
            acc[k][0] = fmaf(gk[k], w.x, acc[k][0]);
            acc[k][1] = fmaf(gk[k], w.y, acc[k][1]);
            acc[k][2] = fmaf(gk[k], w.z, acc[k][2]);
            acc[k][3] = fmaf(gk[k], w.w, acc[k][3]);
        }
    }
    float4 bb = *(const float4*)(b2 + c0);
    float mx0 = -3.4e38f, mx1 = -3.4e38f, mx2 = -3.4e38f, mx3 = -3.4e38f;
#pragma unroll
    for (int k = 0; k < K_; ++k) {
        float h0 = fmaxf(acc[k][0] + bb.x, 0.0f);
        float h1 = fmaxf(acc[k][1] + bb.y, 0.0f);
        float h2 = fmaxf(acc[k][2] + bb.z, 0.0f);
        float h3 = fmaxf(acc[k][3] + bb.w, 0.0f);
        mx0 = fmaxf(mx0, h0); mx1 = fmaxf(mx1, h1);
        mx2 = fmaxf(mx2, h2); mx3 = fmaxf(mx3, h3);
    }
    *(float4*)(f2 + q*C2_ + c0) = make_float4(mx0, mx1, mx2, mx3);
}

// ---------------------------------------------------------------- fused adaptive max+avg pool
__global__ __launch_bounds__(256) void pool_kernel(const float* __restrict__ f2,
                                                   float* __restrict__ out) {
    int bo = blockIdx.x;
    int b = bo / OUT_, o = bo % OUT_;
    int c = threadIdx.x;
    float mx = -3.4e38f, sm = 0.0f;
#pragma unroll
    for (int w = 0; w < M_/OUT_; ++w) {
        float v = f2[(b*M_ + o*(M_/OUT_) + w)*C2_ + c];
        mx = fmaxf(mx, v);
        sm += v;
    }
    out[(b*C2_ + c)*OUT_ + o] = mx + sm / (float)(M_/OUT_);
}

// ---------------------------------------------------------------- launch
extern "C" void kernel_launch(void* const* d_in, const int* in_sizes, int n_in,
                              void* d_out, int out_size, void* d_ws, size_t ws_size,
                              hipStream_t stream) {
    const float* x  = (const float*)d_in[0];
    const float* W1 = (const float*)d_in[1];
    const float* b1 = (const float*)d_in[2];
    const float* W2 = (const float*)d_in[3];
    const float* b2 = (const float*)d_in[4];
    float* out = (float*)d_out;

    char* ws = (char*)d_ws;
    size_t off = 0;
    auto alloc = [&](size_t bytes) {
        void* p = ws + off;
        off += (bytes + 255) & ~(size_t)255;
        return p;
    };
    float4* coords4 = (float4*)alloc((size_t)B_*N_*sizeof(float4));     // 2 MB
    float4* sub4    = (float4*)alloc((size_t)B_*SUBP_*sizeof(float4));  // 256 KB
    int*    fpsIdx  = (int*)  alloc((size_t)B_*M_*sizeof(int));
    int*    idx1    = (int*)  alloc((size_t)B_*M_*K_*sizeof(int));      // 2 MB
    int*    idx2    = (int*)  alloc((size_t)B_*M_*K_*sizeof(int));      // 2 MB
    float*  f1      = (float*)alloc((size_t)B_*M_*C1_*sizeof(float));   // 8 MB
    float*  f2      = (float*)alloc((size_t)B_*M_*C2_*sizeof(float));   // 16 MB

    prep_kernel<<<(B_*N_ + 255)/256, 256, 0, stream>>>(x, coords4, sub4);
    fps_kernel<<<B_, FPS_T, 0, stream>>>(coords4, fpsIdx, sub4);
    knn_kernel<N_/64,    N_   ><<<B_*M_/4, 256, 0, stream>>>(coords4, sub4, idx1);
    knn_kernel<SUBP_/64, SUBP_><<<B_*M_/4, 256, 0, stream>>>(sub4,    sub4, idx2);
    layer1_kernel<<<B_*M_, 128, 0, stream>>>(coords4, sub4, idx1, W1, b1, f1);
    layer2_kernel<<<B_*M_,  64, 0, stream>>>(sub4, f1, idx2, W2, b2, f2);
    pool_kernel<<<B_*OUT_, 256, 0, stream>>>(f2, out);
}